// Round 13
// baseline (6028.397 us; speedup 1.0000x reference)
//
#include <hip/hip_runtime.h>
#include <math.h>

// ---------------------------------------------------------------------------
// CDDD decoder v13: 3-layer GRU (512/1024/2048) greedy decode, B=64, 64 steps.
//
// L1/L2 via bf16 MFMA 16x16x32, split-fp32 weights (hi/lo bf16, 3-term
// product, fp32 accum) — numerics verified exact (r9-r12 absmax 0).
// v13 vs v11 (r12's counted-vmcnt reverted — it over-drained):
//   * comb fused into mfma kernels: per-jb device-scope atomic counter,
//     the last of the 6 blocks (3 gates x 2 kq) does gates+h+frag scatter.
//     4 launches/step instead of 6.
//   * bigger stage groups (L1 GB=6, L2 GB=8 k-blocks) -> fewer barrier
//     drains; x|h select is per-kb (wave-uniform branch).
//
// Fragment convention (sigma-consistent): slot (lane l, elem i) <-> k =
// kblk*32 + (l>>4)*8 + i. A: row m = l&15; B: col n = l&15.
// D (verified): row m = (l>>4)*4 + t, col n = l&15.
// Activation fp32 "T4" layout: buf[(q*64+b)*4+c] == value[b][q*4+c].
// ---------------------------------------------------------------------------

#define BATCH 64

typedef short bf16x8 __attribute__((ext_vector_type(8)));
typedef float f32x4  __attribute__((ext_vector_type(4)));

__device__ __forceinline__ float sigmoid_f(float x) { return 1.0f / (1.0f + expf(-x)); }

__device__ __forceinline__ void fma4(float& a, const float4 w, const float4 x) {
    a = fmaf(w.x, x.x, a); a = fmaf(w.y, x.y, a);
    a = fmaf(w.z, x.z, a); a = fmaf(w.w, x.w, a);
}

__device__ __forceinline__ unsigned short f2bf(float x) {
    unsigned u = __float_as_uint(x);
    return (unsigned short)((u + 0x7fff + ((u >> 16) & 1)) >> 16);
}
__device__ __forceinline__ float bf2f(unsigned short h) {
    return __uint_as_float(((unsigned)h) << 16);
}
__device__ __forceinline__ void split_bf(float v, short& hi, short& lo) {
    unsigned short h = f2bf(v);
    hi = (short)h;
    lo = (short)f2bf(v - bf2f(h));
}

// Scatter one activation value into B-fragment arrays (hi/lo planes).
__device__ __forceinline__ void frag_scatter(short* xhi, short* xlo,
                                             int j, int b, float v) {
    short h, l2; split_bf(v, h, l2);
    const int kblk = j >> 5, off = j & 31;
    const int lp = ((off >> 3) << 4) + (b & 15);
    const int ii = off & 7;
    const int nt = b >> 4;
    const size_t idx = (((size_t)kblk * 4 + nt) * 64 + lp) * 8 + ii;
    xhi[idx] = h; xlo[idx] = l2;
}

// ---------------------------------------------------------------------------
// setup kernels
// ---------------------------------------------------------------------------
__global__ __launch_bounds__(256) void init_misc(
    const float* __restrict__ z, float* __restrict__ zT4,
    int* __restrict__ dec, const int* __restrict__ start_tok)
{
    int tid = blockIdx.x * 256 + threadIdx.x;
    int b  = tid >> 7;
    int k4 = tid & 127;
    ((float4*)zT4)[k4 * 64 + b] = ((const float4*)z)[b * 128 + k4];
    if (tid < BATCH) dec[tid] = start_tok[0];
}

__global__ __launch_bounds__(256) void init_hstate(
    const float* __restrict__ zT4, const float* __restrict__ w,
    const float* __restrict__ bias,
    float* __restrict__ h0, float* __restrict__ h1, float* __restrict__ h2)
{
    const int wave = threadIdx.x >> 6;
    const int b    = threadIdx.x & 63;
    const int r    = blockIdx.x * 4 + wave;      // 0..3583
    const float4* w4 = (const float4*)(w + (size_t)r * 512);
    const float4* z4 = (const float4*)zT4;
    float acc = 0.f;
#pragma unroll 8
    for (int k = 0; k < 128; ++k) fma4(acc, w4[k], z4[k * 64 + b]);
    acc += bias[r];
    float* dst; int j;
    if (r < 512)       { dst = h0; j = r; }
    else if (r < 1536) { dst = h1; j = r - 512; }
    else               { dst = h2; j = r - 1536; }
    dst[(((j >> 2) * 64 + b) << 2) + (j & 3)] = acc;
}

__global__ __launch_bounds__(256) void initfrag(
    const float* __restrict__ hT4, short* __restrict__ xhi, short* __restrict__ xlo)
{
    const int gid = blockIdx.x * 256 + threadIdx.x;
    const int j = gid >> 6, b = gid & 63;
    const float v = hT4[(((j >> 2) * 64 + b) << 2) + (j & 3)];
    frag_scatter(xhi, xlo, j, b, v);
}

__global__ void zero_cnt(int* c1, int* c2) {
    if (threadIdx.x < 64)  c1[threadIdx.x] = 0;
    if (threadIdx.x < 128) c2[threadIdx.x] = 0;
}

// Weight transform: concat-K rows -> frag arrays Wf[unit][kblk][lane][8]
template<int H, int IN>
__device__ __forceinline__ void wtransform_body(
    const float* __restrict__ w_ih, const float* __restrict__ w_hh,
    short* __restrict__ dhi, short* __restrict__ dlo)
{
    constexpr int KB = (IN + H) / 32;
    const int unit = blockIdx.x * 4 + (threadIdx.x >> 6);
    const int l    = threadIdx.x & 63;
    const int mtile = unit / KB, kblk = unit % KB;
    const int row = mtile * 16 + (l & 15);
    const int kk  = kblk * 32 + ((l >> 4) << 3);
    const float* src = (kk < IN) ? (w_ih + (size_t)row * IN + kk)
                                 : (w_hh + (size_t)row * H + (kk - IN));
    const float4 v0 = *(const float4*)src;
    const float4 v1 = *(const float4*)(src + 4);
    const float vv[8] = {v0.x, v0.y, v0.z, v0.w, v1.x, v1.y, v1.z, v1.w};
    short hi[8], lo[8];
#pragma unroll
    for (int i = 0; i < 8; ++i) split_bf(vv[i], hi[i], lo[i]);
    const size_t base = ((size_t)unit * 64 + l) * 8;
    *(bf16x8*)(dhi + base) = *(const bf16x8*)hi;
    *(bf16x8*)(dlo + base) = *(const bf16x8*)lo;
}
__global__ __launch_bounds__(256) void wtrans_l1(
    const float* __restrict__ a, const float* __restrict__ b,
    short* __restrict__ c, short* __restrict__ d)
{ wtransform_body<1024, 512>(a, b, c, d); }
__global__ __launch_bounds__(256) void wtrans_l2(
    const float* __restrict__ a, const float* __restrict__ b,
    short* __restrict__ c, short* __restrict__ d)
{ wtransform_body<2048, 1024>(a, b, c, d); }

// ---------------------------------------------------------------------------
// v13 MFMA kernel body. Block = (gate g, jb, kq): 16 units x 64 b over one
// K-quarter. 8 waves = 4 nt x 2 kh. A staged to LDS via global_load_lds in
// double-buffered GB-kb groups (syncthreads cadence, r11-proven). B register-
// loaded (L2-hot), x|h selected per-kb. Tail block (6th arrival per jb via
// device-scope atomic) performs the combine: gates + h update + frag scatter.
// ---------------------------------------------------------------------------
template<int H, int IN, int GB>
__device__ __forceinline__ void mfma_gate_body(
    const short* __restrict__ Whi, const short* __restrict__ Wlo,
    const short* __restrict__ XxHi, const short* __restrict__ XxLo,
    const short* __restrict__ XhHi, const short* __restrict__ XhLo,
    float* __restrict__ G,
    const float* __restrict__ b_ih, const float* __restrict__ b_hh,
    float* __restrict__ hT4, short* __restrict__ xhi, short* __restrict__ xlo,
    int* __restrict__ cnt)
{
    constexpr int KB  = (IN + H) / 32;
    constexpr int KXB = IN / 32;
    constexpr int GS  = H / 16;
    constexpr int KQ4 = KB / 4;       // kb per (kq,kh) range
    constexpr int NG  = KQ4 / GB;     // groups (L1: 12/6=2, L2: 24/8=3)

    __shared__ __align__(16) short Ast[2][2][GB][2][512];
    __shared__ float red[4][8][64];
    __shared__ int tailflag;

    const int tid = threadIdx.x;
    const int wid = tid >> 6;
    const int l   = tid & 63;
    const int nt  = wid & 3;
    const int kh  = wid >> 2;
    const int kq   = blockIdx.x & 1;
    const int rest = blockIdx.x >> 1;
    const int g    = rest / GS;
    const int jb   = rest % GS;

    const int kbase = kq * (KB / 2) + kh * KQ4;
    const size_t abase = ((size_t)(g * GS + jb) * KB) * 512;   // shorts
    const int pl  = nt & 1;
    const int kl0 = nt >> 1;
    const short* wsrc = (pl ? Wlo : Whi) + abase;

    f32x4 aXa = {0,0,0,0}, aXb = {0,0,0,0}, aHa = {0,0,0,0}, aHb = {0,0,0,0};

    // issue GB/2 async 1KB chunk loads for group grp into Ast[buf][kh]
    auto stage = [&](int buf, int grp) {
        const int kbb = kbase + grp * GB;
#pragma unroll
        for (int u = 0; u < GB / 2; ++u) {
            const int kloc = kl0 + u * 2;
            const short* ga = wsrc + (size_t)(kbb + kloc) * 512 + (size_t)l * 8;
            __builtin_amdgcn_global_load_lds(
                (const __attribute__((address_space(1))) unsigned int*)ga,
                (__attribute__((address_space(3))) unsigned int*)&Ast[buf][kh][kloc][pl][0],
                16, 0, 0);
        }
    };

    // consume group: GB kb x 3 MFMA; A from LDS, B from global; x|h per kb
    auto comp = [&](int buf, int grp) {
        const int kb0 = kbase + grp * GB;
#pragma unroll
        for (int i = 0; i < GB; ++i) {
            const int kbb = kb0 + i;
            const bf16x8 ah = *(const bf16x8*)&Ast[buf][kh][i][0][(size_t)l * 8];
            const bf16x8 al = *(const bf16x8*)&Ast[buf][kh][i][1][(size_t)l * 8];
            if (kbb < KXB) {
                const size_t bo = (size_t)kbb * 2048 + (size_t)nt * 512 + (size_t)l * 8;
                const bf16x8 bh = *(const bf16x8*)(XxHi + bo);
                const bf16x8 bl = *(const bf16x8*)(XxLo + bo);
                aXa = __builtin_amdgcn_mfma_f32_16x16x32_bf16(ah, bh, aXa, 0, 0, 0);
                aXb = __builtin_amdgcn_mfma_f32_16x16x32_bf16(ah, bl, aXb, 0, 0, 0);
                aXb = __builtin_amdgcn_mfma_f32_16x16x32_bf16(al, bh, aXb, 0, 0, 0);
            } else {
                const size_t bo = (size_t)(kbb - KXB) * 2048 + (size_t)nt * 512 + (size_t)l * 8;
                const bf16x8 bh = *(const bf16x8*)(XhHi + bo);
                const bf16x8 bl = *(const bf16x8*)(XhLo + bo);
                aHa = __builtin_amdgcn_mfma_f32_16x16x32_bf16(ah, bh, aHa, 0, 0, 0);
                aHb = __builtin_amdgcn_mfma_f32_16x16x32_bf16(ah, bl, aHb, 0, 0, 0);
                aHb = __builtin_amdgcn_mfma_f32_16x16x32_bf16(al, bh, aHb, 0, 0, 0);
            }
        }
    };

    stage(0, 0);
    __syncthreads();
#pragma unroll
    for (int grp = 0; grp < NG; ++grp) {
        const int buf = grp & 1;
        if (grp + 1 < NG) stage(buf ^ 1, grp + 1);
        comp(buf, grp);
        __syncthreads();
    }

    float SX[4], SH[4];
#pragma unroll
    for (int t = 0; t < 4; ++t) { SX[t] = aXa[t] + aXb[t]; SH[t] = aHa[t] + aHb[t]; }

    if (kh == 1) {
#pragma unroll
        for (int t = 0; t < 4; ++t) {
            red[nt][t][l]     = SX[t];
            red[nt][4 + t][l] = SH[t];
        }
    }
    __syncthreads();
    if (kh == 0) {
        const int b = nt * 16 + (l & 15);
#pragma unroll
        for (int t = 0; t < 4; ++t) {
            SX[t] += red[nt][t][l];
            SH[t] += red[nt][4 + t][l];
            const int j = jb * 16 + ((l >> 4) << 2) + t;
            if (g == 0)      G[(size_t)((kq * 4 + 0) * H + j) * 64 + b] = SX[t] + SH[t];
            else if (g == 1) G[(size_t)((kq * 4 + 1) * H + j) * 64 + b] = SX[t] + SH[t];
            else {
                G[(size_t)((kq * 4 + 2) * H + j) * 64 + b] = SX[t];
                G[(size_t)((kq * 4 + 3) * H + j) * 64 + b] = SH[t];
            }
        }
    }
    // syncthreads waits vmcnt(0): all G stores of this block are retired.
    __syncthreads();

    if (tid == 0) {
        const int old = __hip_atomic_fetch_add(&cnt[jb], 1, __ATOMIC_ACQ_REL,
                                               __HIP_MEMORY_SCOPE_AGENT);
        tailflag = (old == 5);
        if (old == 5)
            __hip_atomic_store(&cnt[jb], 0, __ATOMIC_RELAXED,
                               __HIP_MEMORY_SCOPE_AGENT);
    }
    __syncthreads();

    if (tailflag) {
        const size_t P = (size_t)H * 64;
#pragma unroll
        for (int v = tid; v < 1024; v += 512) {
            const int j = jb * 16 + (v >> 6);
            const int b = v & 63;
            const size_t o = (size_t)j * 64 + b;
            const float R  = G[0 * P + o] + G[4 * P + o];
            const float Z  = G[1 * P + o] + G[5 * P + o];
            const float NX = G[2 * P + o] + G[6 * P + o];
            const float NH = G[3 * P + o] + G[7 * P + o];
            const float r  = sigmoid_f(R + b_ih[j] + b_hh[j]);
            const float zg = sigmoid_f(Z + b_ih[H + j] + b_hh[H + j]);
            const float n  = tanhf(NX + b_ih[2 * H + j] + r * (NH + b_hh[2 * H + j]));
            const int idx = (((j >> 2) * 64 + b) << 2) + (j & 3);
            const float hp = hT4[idx];
            const float hn = (1.f - zg) * n + zg * hp;
            hT4[idx] = hn;
            frag_scatter(xhi, xlo, j, b, hn);
        }
    }
}
__global__ __launch_bounds__(512, 2) void mfma_l1(
    const short* __restrict__ a, const short* __restrict__ b,
    const short* __restrict__ c, const short* __restrict__ d,
    const short* __restrict__ e, const short* __restrict__ f,
    float* __restrict__ g, const float* __restrict__ bi,
    const float* __restrict__ bh, float* __restrict__ h,
    short* __restrict__ xh, short* __restrict__ xl, int* __restrict__ cnt)
{ mfma_gate_body<1024, 512, 6>(a, b, c, d, e, f, g, bi, bh, h, xh, xl, cnt); }
__global__ __launch_bounds__(512, 2) void mfma_l2(
    const short* __restrict__ a, const short* __restrict__ b,
    const short* __restrict__ c, const short* __restrict__ d,
    const short* __restrict__ e, const short* __restrict__ f,
    float* __restrict__ g, const float* __restrict__ bi,
    const float* __restrict__ bh, float* __restrict__ h,
    short* __restrict__ xh, short* __restrict__ xl, int* __restrict__ cnt)
{ mfma_gate_body<2048, 1024, 8>(a, b, c, d, e, f, g, bi, bh, h, xh, xl, cnt); }

// ---------------------------------------------------------------------------
// broadcast GRU body (round-3 proven): L0 + fallback.
// ---------------------------------------------------------------------------
template<int IN, int H, int C, bool L0>
__device__ __forceinline__ void gru2_body(
    const float* __restrict__ xT4,
    const float* __restrict__ emb, const int* __restrict__ dec,
    const float* __restrict__ hT4_in, float* __restrict__ hT4_out,
    const float* __restrict__ w_ih, const float* __restrict__ w_hh,
    const float* __restrict__ b_ih, const float* __restrict__ b_hh,
    short* __restrict__ xw_hi, short* __restrict__ xw_lo)
{
    constexpr int Q  = (IN + H) / 4;
    constexpr int QX = IN / 4;
    constexpr int QW = Q / 8;

    const int tid  = threadIdx.x;
    const int wave = tid >> 6;
    const int b    = tid & 63;
    const int j0   = blockIdx.x * C;
    const int q0 = wave * QW;
    const int q1 = q0 + QW;

    float accR[C], accZ[C], accNX[C], accNH[C];
#pragma unroll
    for (int c = 0; c < C; ++c) { accR[c]=0.f; accZ[c]=0.f; accNX[c]=0.f; accNH[c]=0.f; }

    {
        const int xe = (q1 < QX) ? q1 : QX;
        if (q0 < xe) {
            const float4* xsrc;
            if (L0) { xsrc = (const float4*)(emb + dec[b] * 32); }
            else    { xsrc = (const float4*)xT4; }
            for (int q = q0; q < xe; ++q) {
                const float4 x = L0 ? xsrc[q] : xsrc[q * 64 + b];
#pragma unroll
                for (int c = 0; c < C; ++c) {
                    const int j = j0 + c;
                    fma4(accR[c],  *(const float4*)(w_ih + ((size_t)j * IN) + 4*q), x);
                    fma4(accZ[c],  *(const float4*)(w_ih + ((size_t)(j + H) * IN) + 4*q), x);
                    fma4(accNX[c], *(const float4*)(w_ih + ((size_t)(j + 2*H) * IN) + 4*q), x);
                }
            }
        }
    }
    {
        const int hs0 = (q0 > QX) ? q0 : QX;
        if (hs0 < q1) {
            const float4* h4 = (const float4*)hT4_in;
#pragma unroll 2
            for (int q = hs0; q < q1; ++q) {
                const int qh = q - QX;
                const float4 hv = h4[qh * 64 + b];
#pragma unroll
                for (int c = 0; c < C; ++c) {
                    const int j = j0 + c;
                    fma4(accR[c],  *(const float4*)(w_hh + ((size_t)j * H) + 4*qh), hv);
                    fma4(accZ[c],  *(const float4*)(w_hh + ((size_t)(j + H) * H) + 4*qh), hv);
                    fma4(accNH[c], *(const float4*)(w_hh + ((size_t)(j + 2*H) * H) + 4*qh), hv);
                }
            }
        }
    }

    __shared__ float red[8][C][4][64];
#pragma unroll
    for (int c = 0; c < C; ++c) {
        red[wave][c][0][b] = accR[c];
        red[wave][c][1][b] = accZ[c];
        red[wave][c][2][b] = accNX[c];
        red[wave][c][3][b] = accNH[c];
    }
    __syncthreads();

    if (tid < C * 64) {
        const int c  = tid >> 6;
        const int bb = tid & 63;
        float R = 0.f, Z = 0.f, NX = 0.f, NH = 0.f;
#pragma unroll
        for (int w = 0; w < 8; ++w) {
            R += red[w][c][0][bb]; Z += red[w][c][1][bb];
            NX += red[w][c][2][bb]; NH += red[w][c][3][bb];
        }
        const int j = j0 + c;
        const float r  = sigmoid_f(R + b_ih[j]     + b_hh[j]);
        const float zg = sigmoid_f(Z + b_ih[j + H] + b_hh[j + H]);
        const float n  = tanhf(NX + b_ih[j + 2 * H] + r * (NH + b_hh[j + 2 * H]));
        const float hp = hT4_in[(((j >> 2) * 64 + bb) << 2) + (j & 3)];
        const float hn = (1.f - zg) * n + zg * hp;
        hT4_out[(((j >> 2) * 64 + bb) << 2) + (j & 3)] = hn;
        if (xw_hi) frag_scatter(xw_hi, xw_lo, j, bb, hn);
    }
}
__global__ __launch_bounds__(512) void gru_l0(
    const float* __restrict__ emb, const int* __restrict__ dec,
    const float* __restrict__ hin, float* __restrict__ hout,
    const float* __restrict__ wi, const float* __restrict__ wh,
    const float* __restrict__ bi, const float* __restrict__ bh,
    short* __restrict__ xh, short* __restrict__ xl)
{ gru2_body<32, 512, 2, true>(nullptr, emb, dec, hin, hout, wi, wh, bi, bh, xh, xl); }
__global__ __launch_bounds__(512) void gru_fb1(
    const float* __restrict__ x, const float* __restrict__ hin, float* __restrict__ hout,
    const float* __restrict__ wi, const float* __restrict__ wh,
    const float* __restrict__ bi, const float* __restrict__ bh)
{ gru2_body<512, 1024, 4, false>(x, nullptr, nullptr, hin, hout, wi, wh, bi, bh, nullptr, nullptr); }
__global__ __launch_bounds__(512) void gru_fb2(
    const float* __restrict__ x, const float* __restrict__ hin, float* __restrict__ hout,
    const float* __restrict__ wi, const float* __restrict__ wh,
    const float* __restrict__ bi, const float* __restrict__ bh)
{ gru2_body<1024, 2048, 4, false>(x, nullptr, nullptr, hin, hout, wi, wh, bi, bh, nullptr, nullptr); }

// Fused logits + argmax. One block per batch row.
__global__ __launch_bounds__(512) void out_k(
    const float* __restrict__ h2T4, const float* __restrict__ w_out,
    int* __restrict__ dec, int* __restrict__ out, int s, int max_len)
{
    __shared__ float hs[2048];
    __shared__ float lg[40];
    const int b    = blockIdx.x;
    const int tid  = threadIdx.x;
    const int wave = tid >> 6;
    const int lane = tid & 63;

    const float4* h4 = (const float4*)h2T4;
    ((float4*)hs)[tid] = h4[tid * 64 + b];
    __syncthreads();

    const float4* hs4 = (const float4*)hs;
#pragma unroll
    for (int v = wave * 5; v < wave * 5 + 5; ++v) {
        const float4* w4 = (const float4*)(w_out + (size_t)v * 2048);
        float acc = 0.f;
#pragma unroll
        for (int it = 0; it < 8; ++it) {
            const int k4 = it * 64 + lane;
            fma4(acc, w4[k4], hs4[k4]);
        }
#pragma unroll
        for (int off = 32; off > 0; off >>= 1)
            acc += __shfl_down(acc, off, 64);
        if (lane == 0) lg[v] = acc;
    }
    __syncthreads();

    if (tid == 0) {
        float best = lg[0];
        int bi = 0;
#pragma unroll
        for (int v = 1; v < 40; ++v) {
            const float val = lg[v];
            if (val > best) { best = val; bi = v; }
        }
        dec[b] = bi;
        out[b * max_len + s] = bi;
    }
}

// ---------------------------------------------------------------------------
// host
// ---------------------------------------------------------------------------
extern "C" void kernel_launch(void* const* d_in, const int* in_sizes, int n_in,
                              void* d_out, int out_size, void* d_ws, size_t ws_size,
                              hipStream_t stream)
{
    const float* z         = (const float*)d_in[0];
    const float* emb       = (const float*)d_in[1];
    const float* fc_init_w = (const float*)d_in[2];
    const float* fc_init_b = (const float*)d_in[3];
    const float* fc_out_w  = (const float*)d_in[4];
    const float* w_ih0 = (const float*)d_in[5];
    const float* w_hh0 = (const float*)d_in[6];
    const float* b_ih0 = (const float*)d_in[7];
    const float* b_hh0 = (const float*)d_in[8];
    const float* w_ih1 = (const float*)d_in[9];
    const float* w_hh1 = (const float*)d_in[10];
    const float* b_ih1 = (const float*)d_in[11];
    const float* b_hh1 = (const float*)d_in[12];
    const float* w_ih2 = (const float*)d_in[13];
    const float* w_hh2 = (const float*)d_in[14];
    const float* b_ih2 = (const float*)d_in[15];
    const float* b_hh2 = (const float*)d_in[16];
    const int* start_tok = (const int*)d_in[18];

    int* out = (int*)d_out;
    const int max_len = out_size / BATCH;   // 64
    char* ws = (char*)d_ws;

    const size_t NEED = 103547904;

    if (ws_size >= NEED) {
        short* Wf1hi = (short*)(ws + 0);          //  9,437,184 B
        short* Wf1lo = (short*)(ws + 9437184);
        short* Wf2hi = (short*)(ws + 18874368);   // 37,748,736 B
        short* Wf2lo = (short*)(ws + 56623104);
        short* XB0hi = (short*)(ws + 94371840);   //     65,536 B
        short* XB0lo = (short*)(ws + 94437376);
        short* XB1hi[2] = { (short*)(ws + 94502912), (short*)(ws + 94765056) };
        short* XB1lo[2] = { (short*)(ws + 94633984), (short*)(ws + 94896128) };
        short* XB2hi[2] = { (short*)(ws + 95027200), (short*)(ws + 95551488) };
        short* XB2lo[2] = { (short*)(ws + 95289344), (short*)(ws + 95813632) };
        float* h0a = (float*)(ws + 96075776);
        float* h0b = (float*)(ws + 96206848);
        float* h1  = (float*)(ws + 96337920);
        float* h2  = (float*)(ws + 96600064);
        float* zT4 = (float*)(ws + 97124352);
        float* G1  = (float*)(ws + 97255424);     // 2,097,152 B (8 planes)
        float* G2  = (float*)(ws + 99352576);     // 4,194,304 B (8 planes)
        int*   dec = (int*)  (ws + 103546880);    // 256 B
        int*   cnt1 = (int*) (ws + 103547136);    // 256 B (64 jb)
        int*   cnt2 = (int*) (ws + 103547392);    // 512 B (128 jb)

        // ---- setup ----
        wtrans_l1<<<2304, 256, 0, stream>>>(w_ih1, w_hh1, Wf1hi, Wf1lo);
        wtrans_l2<<<9216, 256, 0, stream>>>(w_ih2, w_hh2, Wf2hi, Wf2lo);
        init_misc<<<32, 256, 0, stream>>>(z, zT4, dec, start_tok);
        init_hstate<<<896, 256, 0, stream>>>(zT4, fc_init_w, fc_init_b, h0a, h1, h2);
        initfrag<<<256, 256, 0, stream>>>(h1, XB1hi[0], XB1lo[0]);
        initfrag<<<512, 256, 0, stream>>>(h2, XB2hi[0], XB2lo[0]);
        zero_cnt<<<1, 128, 0, stream>>>(cnt1, cnt2);

        for (int s = 0; s < max_len; ++s) {
            const int pi = s & 1, po = pi ^ 1;
            const float* h0i = pi ? h0b : h0a;
            float*       h0o = pi ? h0a : h0b;
            gru_l0<<<256, 512, 0, stream>>>(emb, dec, h0i, h0o,
                                            w_ih0, w_hh0, b_ih0, b_hh0,
                                            XB0hi, XB0lo);
            mfma_l1<<<384, 512, 0, stream>>>(Wf1hi, Wf1lo, XB0hi, XB0lo,
                                             XB1hi[pi], XB1lo[pi], G1,
                                             b_ih1, b_hh1, h1,
                                             XB1hi[po], XB1lo[po], cnt1);
            mfma_l2<<<768, 512, 0, stream>>>(Wf2hi, Wf2lo, XB1hi[po], XB1lo[po],
                                             XB2hi[pi], XB2lo[pi], G2,
                                             b_ih2, b_hh2, h2,
                                             XB2hi[po], XB2lo[po], cnt2);
            out_k<<<64, 512, 0, stream>>>(h2, fc_out_w, dec, out, s, max_len);
        }
    } else {
        // -------- fallback: round-3 path --------
        float* zT4    = (float*)(ws + 0);
        float* h0b2[2] = { (float*)(ws + 131072), (float*)(ws + 262144) };
        float* h1b2[2] = { (float*)(ws + 393216), (float*)(ws + 655360) };
        float* h2b2[2] = { (float*)(ws + 917504), (float*)(ws + 1441792) };
        int*   dec    = (int*)(ws + 1966080);

        init_misc<<<32, 256, 0, stream>>>(z, zT4, dec, start_tok);
        init_hstate<<<896, 256, 0, stream>>>(zT4, fc_init_w, fc_init_b,
                                             h0b2[0], h1b2[0], h2b2[0]);
        for (int s = 0; s < max_len; ++s) {
            const int pi = s & 1, po = pi ^ 1;
            gru_l0<<<256, 512, 0, stream>>>(emb, dec, h0b2[pi], h0b2[po],
                                            w_ih0, w_hh0, b_ih0, b_hh0,
                                            nullptr, nullptr);
            gru_fb1<<<256, 512, 0, stream>>>(h0b2[po], h1b2[pi], h1b2[po],
                                             w_ih1, w_hh1, b_ih1, b_hh1);
            gru_fb2<<<512, 512, 0, stream>>>(h1b2[po], h2b2[pi], h2b2[po],
                                             w_ih2, w_hh2, b_ih2, b_hh2);
            out_k<<<64, 512, 0, stream>>>(h2b2[po], fc_out_w, dec, out, s, max_len);
        }
    }
}

// Round 14
// 3182.993 us; speedup vs baseline: 1.8939x; 1.8939x over previous
//
#include <hip/hip_runtime.h>
#include <math.h>

// ---------------------------------------------------------------------------
// CDDD decoder v14: 3-layer GRU (512/1024/2048) greedy decode, B=64, 64 steps.
//
// Base = r11 (3.21ms, proven): L1/L2 bf16 MFMA 16x16x32, split-fp32 weights
// (hi/lo bf16, 3-term product, fp32 accum; absmax 0 across r9-r13).
// A-fragments staged HBM/L3 -> LDS via global_load_lds, double-buffered
// 4-kb groups, __syncthreads cadence. r12's counted-vmcnt and r13's
// per-block agent atomics (L2-writeback/invalidate storm) are both reverted.
//
// v14 single change: mfma_l2 uses MT=2 (32 GRU units per block, 2 m-tiles).
//  -> block count 768->384: fits in ONE co-resident wave (r11's 768 at
//     2 blocks/CU exceeded 512 slots -> 1.5-pass serialization).
//  -> B-fragment L2 traffic halves (~295 -> ~148 MB/step).
// LDS 64KB/block (2/CU); reduce buffer aliases the dead A-ring.
//
// Fragment convention (sigma-consistent): slot (lane l, elem i) <-> k =
// kblk*32 + (l>>4)*8 + i. A: row m = l&15; B: col n = l&15.
// D (verified): row m = (l>>4)*4 + t, col n = l&15.
// Activation fp32 "T4" layout: buf[(q*64+b)*4+c] == value[b][q*4+c].
// ---------------------------------------------------------------------------

#define BATCH 64

typedef short bf16x8 __attribute__((ext_vector_type(8)));
typedef float f32x4  __attribute__((ext_vector_type(4)));

__device__ __forceinline__ float sigmoid_f(float x) { return 1.0f / (1.0f + expf(-x)); }

__device__ __forceinline__ void fma4(float& a, const float4 w, const float4 x) {
    a = fmaf(w.x, x.x, a); a = fmaf(w.y, x.y, a);
    a = fmaf(w.z, x.z, a); a = fmaf(w.w, x.w, a);
}

__device__ __forceinline__ unsigned short f2bf(float x) {
    unsigned u = __float_as_uint(x);
    return (unsigned short)((u + 0x7fff + ((u >> 16) & 1)) >> 16);
}
__device__ __forceinline__ float bf2f(unsigned short h) {
    return __uint_as_float(((unsigned)h) << 16);
}
__device__ __forceinline__ void split_bf(float v, short& hi, short& lo) {
    unsigned short h = f2bf(v);
    hi = (short)h;
    lo = (short)f2bf(v - bf2f(h));
}

// Scatter one activation value into B-fragment arrays (hi/lo planes).
__device__ __forceinline__ void frag_scatter(short* xhi, short* xlo,
                                             int j, int b, float v) {
    short h, l2; split_bf(v, h, l2);
    const int kblk = j >> 5, off = j & 31;
    const int lp = ((off >> 3) << 4) + (b & 15);
    const int ii = off & 7;
    const int nt = b >> 4;
    const size_t idx = (((size_t)kblk * 4 + nt) * 64 + lp) * 8 + ii;
    xhi[idx] = h; xlo[idx] = l2;
}

// ---------------------------------------------------------------------------
// setup kernels
// ---------------------------------------------------------------------------
__global__ __launch_bounds__(256) void init_misc(
    const float* __restrict__ z, float* __restrict__ zT4,
    int* __restrict__ dec, const int* __restrict__ start_tok)
{
    int tid = blockIdx.x * 256 + threadIdx.x;
    int b  = tid >> 7;
    int k4 = tid & 127;
    ((float4*)zT4)[k4 * 64 + b] = ((const float4*)z)[b * 128 + k4];
    if (tid < BATCH) dec[tid] = start_tok[0];
}

__global__ __launch_bounds__(256) void init_hstate(
    const float* __restrict__ zT4, const float* __restrict__ w,
    const float* __restrict__ bias,
    float* __restrict__ h0, float* __restrict__ h1, float* __restrict__ h2)
{
    const int wave = threadIdx.x >> 6;
    const int b    = threadIdx.x & 63;
    const int r    = blockIdx.x * 4 + wave;      // 0..3583
    const float4* w4 = (const float4*)(w + (size_t)r * 512);
    const float4* z4 = (const float4*)zT4;
    float acc = 0.f;
#pragma unroll 8
    for (int k = 0; k < 128; ++k) fma4(acc, w4[k], z4[k * 64 + b]);
    acc += bias[r];
    float* dst; int j;
    if (r < 512)       { dst = h0; j = r; }
    else if (r < 1536) { dst = h1; j = r - 512; }
    else               { dst = h2; j = r - 1536; }
    dst[(((j >> 2) * 64 + b) << 2) + (j & 3)] = acc;
}

__global__ __launch_bounds__(256) void initfrag(
    const float* __restrict__ hT4, short* __restrict__ xhi, short* __restrict__ xlo)
{
    const int gid = blockIdx.x * 256 + threadIdx.x;
    const int j = gid >> 6, b = gid & 63;
    const float v = hT4[(((j >> 2) * 64 + b) << 2) + (j & 3)];
    frag_scatter(xhi, xlo, j, b, v);
}

// Weight transform: concat-K rows -> frag arrays Wf[unit][kblk][lane][8]
template<int H, int IN>
__device__ __forceinline__ void wtransform_body(
    const float* __restrict__ w_ih, const float* __restrict__ w_hh,
    short* __restrict__ dhi, short* __restrict__ dlo)
{
    constexpr int KB = (IN + H) / 32;
    const int unit = blockIdx.x * 4 + (threadIdx.x >> 6);
    const int l    = threadIdx.x & 63;
    const int mtile = unit / KB, kblk = unit % KB;
    const int row = mtile * 16 + (l & 15);
    const int kk  = kblk * 32 + ((l >> 4) << 3);
    const float* src = (kk < IN) ? (w_ih + (size_t)row * IN + kk)
                                 : (w_hh + (size_t)row * H + (kk - IN));
    const float4 v0 = *(const float4*)src;
    const float4 v1 = *(const float4*)(src + 4);
    const float vv[8] = {v0.x, v0.y, v0.z, v0.w, v1.x, v1.y, v1.z, v1.w};
    short hi[8], lo[8];
#pragma unroll
    for (int i = 0; i < 8; ++i) split_bf(vv[i], hi[i], lo[i]);
    const size_t base = ((size_t)unit * 64 + l) * 8;
    *(bf16x8*)(dhi + base) = *(const bf16x8*)hi;
    *(bf16x8*)(dlo + base) = *(const bf16x8*)lo;
}
__global__ __launch_bounds__(256) void wtrans_l1(
    const float* __restrict__ a, const float* __restrict__ b,
    short* __restrict__ c, short* __restrict__ d)
{ wtransform_body<1024, 512>(a, b, c, d); }
__global__ __launch_bounds__(256) void wtrans_l2(
    const float* __restrict__ a, const float* __restrict__ b,
    short* __restrict__ c, short* __restrict__ d)
{ wtransform_body<2048, 1024>(a, b, c, d); }

// ---------------------------------------------------------------------------
// v14 MFMA kernel body, templated on MT (m-tiles per block; 16*MT units).
// Block = (gate g, jb, kq): MT*16 units x 64 b over one K-quarter.
// 8 waves = 4 nt x 2 kh. A staged to LDS via global_load_lds, double-
// buffered 4-kb groups, __syncthreads cadence (r11-proven). B register-
// loaded (L2-hot). Writes G planes p = kq*4 + {R,Z,NX,NH}.
// Reduce buffer aliases the A-ring (dead after the k-loop's final barrier).
// ---------------------------------------------------------------------------
template<int H, int IN, int MT>
__device__ __forceinline__ void mfma_gate_body(
    const short* __restrict__ Whi, const short* __restrict__ Wlo,
    const short* __restrict__ XxHi, const short* __restrict__ XxLo,
    const short* __restrict__ XhHi, const short* __restrict__ XhLo,
    float* __restrict__ G)
{
    constexpr int KB  = (IN + H) / 32;
    constexpr int KXB = IN / 32;
    constexpr int GS  = H / 16;       // m-tiles per gate
    constexpr int GS2 = GS / MT;      // jb blocks per gate
    constexpr int KQ4 = KB / 4;       // kb per (kq,kh) range
    constexpr int NG  = KQ4 / 4;      // 4-kb groups per range

    // [buf][kh][kb][mt][pl][512] shorts; red aliases the front.
    __shared__ __align__(16) char smem[2 * 2 * 4 * MT * 2 * 512 * 2];
    auto Ast = (short (*)[2][4][MT][2][512])smem;
    auto red = (float (*)[MT][8][64])smem;     // [nt][mt][8][64]

    const int tid = threadIdx.x;
    const int wid = tid >> 6;
    const int l   = tid & 63;
    const int nt  = wid & 3;
    const int kh  = wid >> 2;
    const int kq   = blockIdx.x & 1;
    const int rest = blockIdx.x >> 1;
    const int g    = rest / GS2;
    const int jb   = rest % GS2;

    const int kbase = kq * (KB / 2) + kh * KQ4;
    const int pl  = nt & 1;
    const int kl0 = nt >> 1;

    const short* wsrc[MT];
#pragma unroll
    for (int mt = 0; mt < MT; ++mt)
        wsrc[mt] = (pl ? Wlo : Whi)
                 + ((size_t)(g * GS + jb * MT + mt) * KB) * 512;

    f32x4 aXa[MT], aXb[MT], aHa[MT], aHb[MT];
#pragma unroll
    for (int mt = 0; mt < MT; ++mt) {
        aXa[mt] = f32x4{0, 0, 0, 0}; aXb[mt] = f32x4{0, 0, 0, 0};
        aHa[mt] = f32x4{0, 0, 0, 0}; aHb[mt] = f32x4{0, 0, 0, 0};
    }

    // issue 2*MT async 1KB chunk loads for group grp into Ast[buf][kh]
    auto stage = [&](int buf, int grp) {
        const int kbb = kbase + grp * 4;
#pragma unroll
        for (int u = 0; u < 2 * MT; ++u) {
            const int kloc = kl0 + (u & 1) * 2;
            const int mt   = u >> 1;
            const short* ga = wsrc[mt] + (size_t)(kbb + kloc) * 512 + (size_t)l * 8;
            __builtin_amdgcn_global_load_lds(
                (const __attribute__((address_space(1))) unsigned int*)ga,
                (__attribute__((address_space(3))) unsigned int*)&Ast[buf][kh][kloc][mt][pl][0],
                16, 0, 0);
        }
    };

    // consume group: 4 kb x (3 MFMA x MT); A from LDS, B from global (L2-hot)
    auto comp = [&](int buf, const short* bsH, const short* bsL,
                    f32x4 (&A1)[MT], f32x4 (&A2)[MT]) {
#pragma unroll
        for (int i = 0; i < 4; ++i) {
            const size_t bo = (size_t)i * 2048 + (size_t)nt * 512 + (size_t)l * 8;
            const bf16x8 bh = *(const bf16x8*)(bsH + bo);
            const bf16x8 bl = *(const bf16x8*)(bsL + bo);
#pragma unroll
            for (int mt = 0; mt < MT; ++mt) {
                const bf16x8 ah = *(const bf16x8*)&Ast[buf][kh][i][mt][0][(size_t)l * 8];
                const bf16x8 al = *(const bf16x8*)&Ast[buf][kh][i][mt][1][(size_t)l * 8];
                A1[mt] = __builtin_amdgcn_mfma_f32_16x16x32_bf16(ah, bh, A1[mt], 0, 0, 0);
                A2[mt] = __builtin_amdgcn_mfma_f32_16x16x32_bf16(ah, bl, A2[mt], 0, 0, 0);
                A2[mt] = __builtin_amdgcn_mfma_f32_16x16x32_bf16(al, bh, A2[mt], 0, 0, 0);
            }
        }
    };

    stage(0, 0);
    __syncthreads();
#pragma unroll
    for (int grp = 0; grp < NG; ++grp) {
        const int buf = grp & 1;
        if (grp + 1 < NG) stage(buf ^ 1, grp + 1);
        const int kbb = kbase + grp * 4;   // groups never straddle KXB (checked)
        if (kbb < KXB)
            comp(buf, XxHi + (size_t)kbb * 2048, XxLo + (size_t)kbb * 2048, aXa, aXb);
        else
            comp(buf, XhHi + (size_t)(kbb - KXB) * 2048,
                      XhLo + (size_t)(kbb - KXB) * 2048, aHa, aHb);
        __syncthreads();
    }
    // A-ring dead from here (loop-final barrier passed); red aliases it.

    float SX[MT][4], SH[MT][4];
#pragma unroll
    for (int mt = 0; mt < MT; ++mt)
#pragma unroll
        for (int t = 0; t < 4; ++t) {
            SX[mt][t] = aXa[mt][t] + aXb[mt][t];
            SH[mt][t] = aHa[mt][t] + aHb[mt][t];
        }

    if (kh == 1) {
#pragma unroll
        for (int mt = 0; mt < MT; ++mt)
#pragma unroll
            for (int t = 0; t < 4; ++t) {
                red[nt][mt][t][l]     = SX[mt][t];
                red[nt][mt][4 + t][l] = SH[mt][t];
            }
    }
    __syncthreads();
    if (kh == 0) {
        const int b = nt * 16 + (l & 15);
#pragma unroll
        for (int mt = 0; mt < MT; ++mt)
#pragma unroll
            for (int t = 0; t < 4; ++t) {
                const float sx = SX[mt][t] + red[nt][mt][t][l];
                const float sh = SH[mt][t] + red[nt][mt][4 + t][l];
                const int j = (jb * MT + mt) * 16 + ((l >> 4) << 2) + t;
                if (g == 0)      G[(size_t)((kq * 4 + 0) * H + j) * 64 + b] = sx + sh;
                else if (g == 1) G[(size_t)((kq * 4 + 1) * H + j) * 64 + b] = sx + sh;
                else {
                    G[(size_t)((kq * 4 + 2) * H + j) * 64 + b] = sx;
                    G[(size_t)((kq * 4 + 3) * H + j) * 64 + b] = sh;
                }
            }
    }
}
__global__ __launch_bounds__(512, 2) void mfma_l1(
    const short* __restrict__ a, const short* __restrict__ b,
    const short* __restrict__ c, const short* __restrict__ d,
    const short* __restrict__ e, const short* __restrict__ f,
    float* __restrict__ g)
{ mfma_gate_body<1024, 512, 1>(a, b, c, d, e, f, g); }
__global__ __launch_bounds__(512, 2) void mfma_l2(
    const short* __restrict__ a, const short* __restrict__ b,
    const short* __restrict__ c, const short* __restrict__ d,
    const short* __restrict__ e, const short* __restrict__ f,
    float* __restrict__ g)
{ mfma_gate_body<2048, 1024, 2>(a, b, c, d, e, f, g); }

// ---------------------------------------------------------------------------
// combine: sum kq planes + gates + fp32 h update in place + frag scatter.
// ---------------------------------------------------------------------------
template<int H>
__device__ __forceinline__ void comb_body(
    const float* __restrict__ G,
    const float* __restrict__ b_ih, const float* __restrict__ b_hh,
    float* __restrict__ hT4, short* __restrict__ xhi, short* __restrict__ xlo)
{
    const int gid = blockIdx.x * 256 + threadIdx.x;
    const int j = gid >> 6, b = gid & 63;
    const size_t o = (size_t)j * 64 + b;
    const size_t P = (size_t)H * 64;
    const float R  = G[0 * P + o] + G[4 * P + o];
    const float Z  = G[1 * P + o] + G[5 * P + o];
    const float NX = G[2 * P + o] + G[6 * P + o];
    const float NH = G[3 * P + o] + G[7 * P + o];
    const float r  = sigmoid_f(R + b_ih[j] + b_hh[j]);
    const float zg = sigmoid_f(Z + b_ih[H + j] + b_hh[H + j]);
    const float n  = tanhf(NX + b_ih[2 * H + j] + r * (NH + b_hh[2 * H + j]));
    const int idx = (((j >> 2) * 64 + b) << 2) + (j & 3);
    const float hp = hT4[idx];
    const float hn = (1.f - zg) * n + zg * hp;
    hT4[idx] = hn;
    frag_scatter(xhi, xlo, j, b, hn);
}
__global__ __launch_bounds__(256) void comb_l1(
    const float* __restrict__ G, const float* __restrict__ bi,
    const float* __restrict__ bh, float* __restrict__ h,
    short* __restrict__ xh, short* __restrict__ xl)
{ comb_body<1024>(G, bi, bh, h, xh, xl); }
__global__ __launch_bounds__(256) void comb_l2(
    const float* __restrict__ G, const float* __restrict__ bi,
    const float* __restrict__ bh, float* __restrict__ h,
    short* __restrict__ xh, short* __restrict__ xl)
{ comb_body<2048>(G, bi, bh, h, xh, xl); }

// ---------------------------------------------------------------------------
// broadcast GRU body (round-3 proven): L0 + fallback.
// ---------------------------------------------------------------------------
template<int IN, int H, int C, bool L0>
__device__ __forceinline__ void gru2_body(
    const float* __restrict__ xT4,
    const float* __restrict__ emb, const int* __restrict__ dec,
    const float* __restrict__ hT4_in, float* __restrict__ hT4_out,
    const float* __restrict__ w_ih, const float* __restrict__ w_hh,
    const float* __restrict__ b_ih, const float* __restrict__ b_hh,
    short* __restrict__ xw_hi, short* __restrict__ xw_lo)
{
    constexpr int Q  = (IN + H) / 4;
    constexpr int QX = IN / 4;
    constexpr int QW = Q / 8;

    const int tid  = threadIdx.x;
    const int wave = tid >> 6;
    const int b    = tid & 63;
    const int j0   = blockIdx.x * C;
    const int q0 = wave * QW;
    const int q1 = q0 + QW;

    float accR[C], accZ[C], accNX[C], accNH[C];
#pragma unroll
    for (int c = 0; c < C; ++c) { accR[c]=0.f; accZ[c]=0.f; accNX[c]=0.f; accNH[c]=0.f; }

    {
        const int xe = (q1 < QX) ? q1 : QX;
        if (q0 < xe) {
            const float4* xsrc;
            if (L0) { xsrc = (const float4*)(emb + dec[b] * 32); }
            else    { xsrc = (const float4*)xT4; }
            for (int q = q0; q < xe; ++q) {
                const float4 x = L0 ? xsrc[q] : xsrc[q * 64 + b];
#pragma unroll
                for (int c = 0; c < C; ++c) {
                    const int j = j0 + c;
                    fma4(accR[c],  *(const float4*)(w_ih + ((size_t)j * IN) + 4*q), x);
                    fma4(accZ[c],  *(const float4*)(w_ih + ((size_t)(j + H) * IN) + 4*q), x);
                    fma4(accNX[c], *(const float4*)(w_ih + ((size_t)(j + 2*H) * IN) + 4*q), x);
                }
            }
        }
    }
    {
        const int hs0 = (q0 > QX) ? q0 : QX;
        if (hs0 < q1) {
            const float4* h4 = (const float4*)hT4_in;
#pragma unroll 2
            for (int q = hs0; q < q1; ++q) {
                const int qh = q - QX;
                const float4 hv = h4[qh * 64 + b];
#pragma unroll
                for (int c = 0; c < C; ++c) {
                    const int j = j0 + c;
                    fma4(accR[c],  *(const float4*)(w_hh + ((size_t)j * H) + 4*qh), hv);
                    fma4(accZ[c],  *(const float4*)(w_hh + ((size_t)(j + H) * H) + 4*qh), hv);
                    fma4(accNH[c], *(const float4*)(w_hh + ((size_t)(j + 2*H) * H) + 4*qh), hv);
                }
            }
        }
    }

    __shared__ float red[8][C][4][64];
#pragma unroll
    for (int c = 0; c < C; ++c) {
        red[wave][c][0][b] = accR[c];
        red[wave][c][1][b] = accZ[c];
        red[wave][c][2][b] = accNX[c];
        red[wave][c][3][b] = accNH[c];
    }
    __syncthreads();

    if (tid < C * 64) {
        const int c  = tid >> 6;
        const int bb = tid & 63;
        float R = 0.f, Z = 0.f, NX = 0.f, NH = 0.f;
#pragma unroll
        for (int w = 0; w < 8; ++w) {
            R += red[w][c][0][bb]; Z += red[w][c][1][bb];
            NX += red[w][c][2][bb]; NH += red[w][c][3][bb];
        }
        const int j = j0 + c;
        const float r  = sigmoid_f(R + b_ih[j]     + b_hh[j]);
        const float zg = sigmoid_f(Z + b_ih[j + H] + b_hh[j + H]);
        const float n  = tanhf(NX + b_ih[j + 2 * H] + r * (NH + b_hh[j + 2 * H]));
        const float hp = hT4_in[(((j >> 2) * 64 + bb) << 2) + (j & 3)];
        const float hn = (1.f - zg) * n + zg * hp;
        hT4_out[(((j >> 2) * 64 + bb) << 2) + (j & 3)] = hn;
        if (xw_hi) frag_scatter(xw_hi, xw_lo, j, bb, hn);
    }
}
__global__ __launch_bounds__(512) void gru_l0(
    const float* __restrict__ emb, const int* __restrict__ dec,
    const float* __restrict__ hin, float* __restrict__ hout,
    const float* __restrict__ wi, const float* __restrict__ wh,
    const float* __restrict__ bi, const float* __restrict__ bh,
    short* __restrict__ xh, short* __restrict__ xl)
{ gru2_body<32, 512, 2, true>(nullptr, emb, dec, hin, hout, wi, wh, bi, bh, xh, xl); }
__global__ __launch_bounds__(512) void gru_fb1(
    const float* __restrict__ x, const float* __restrict__ hin, float* __restrict__ hout,
    const float* __restrict__ wi, const float* __restrict__ wh,
    const float* __restrict__ bi, const float* __restrict__ bh)
{ gru2_body<512, 1024, 4, false>(x, nullptr, nullptr, hin, hout, wi, wh, bi, bh, nullptr, nullptr); }
__global__ __launch_bounds__(512) void gru_fb2(
    const float* __restrict__ x, const float* __restrict__ hin, float* __restrict__ hout,
    const float* __restrict__ wi, const float* __restrict__ wh,
    const float* __restrict__ bi, const float* __restrict__ bh)
{ gru2_body<1024, 2048, 4, false>(x, nullptr, nullptr, hin, hout, wi, wh, bi, bh, nullptr, nullptr); }

// Fused logits + argmax. One block per batch row.
__global__ __launch_bounds__(512) void out_k(
    const float* __restrict__ h2T4, const float* __restrict__ w_out,
    int* __restrict__ dec, int* __restrict__ out, int s, int max_len)
{
    __shared__ float hs[2048];
    __shared__ float lg[40];
    const int b    = blockIdx.x;
    const int tid  = threadIdx.x;
    const int wave = tid >> 6;
    const int lane = tid & 63;

    const float4* h4 = (const float4*)h2T4;
    ((float4*)hs)[tid] = h4[tid * 64 + b];
    __syncthreads();

    const float4* hs4 = (const float4*)hs;
#pragma unroll
    for (int v = wave * 5; v < wave * 5 + 5; ++v) {
        const float4* w4 = (const float4*)(w_out + (size_t)v * 2048);
        float acc = 0.f;
#pragma unroll
        for (int it = 0; it < 8; ++it) {
            const int k4 = it * 64 + lane;
            fma4(acc, w4[k4], hs4[k4]);
        }
#pragma unroll
        for (int off = 32; off > 0; off >>= 1)
            acc += __shfl_down(acc, off, 64);
        if (lane == 0) lg[v] = acc;
    }
    __syncthreads();

    if (tid == 0) {
        float best = lg[0];
        int bi = 0;
#pragma unroll
        for (int v = 1; v < 40; ++v) {
            const float val = lg[v];
            if (val > best) { best = val; bi = v; }
        }
        dec[b] = bi;
        out[b * max_len + s] = bi;
    }
}

// ---------------------------------------------------------------------------
// host
// ---------------------------------------------------------------------------
extern "C" void kernel_launch(void* const* d_in, const int* in_sizes, int n_in,
                              void* d_out, int out_size, void* d_ws, size_t ws_size,
                              hipStream_t stream)
{
    const float* z         = (const float*)d_in[0];
    const float* emb       = (const float*)d_in[1];
    const float* fc_init_w = (const float*)d_in[2];
    const float* fc_init_b = (const float*)d_in[3];
    const float* fc_out_w  = (const float*)d_in[4];
    const float* w_ih0 = (const float*)d_in[5];
    const float* w_hh0 = (const float*)d_in[6];
    const float* b_ih0 = (const float*)d_in[7];
    const float* b_hh0 = (const float*)d_in[8];
    const float* w_ih1 = (const float*)d_in[9];
    const float* w_hh1 = (const float*)d_in[10];
    const float* b_ih1 = (const float*)d_in[11];
    const float* b_hh1 = (const float*)d_in[12];
    const float* w_ih2 = (const float*)d_in[13];
    const float* w_hh2 = (const float*)d_in[14];
    const float* b_ih2 = (const float*)d_in[15];
    const float* b_hh2 = (const float*)d_in[16];
    const int* start_tok = (const int*)d_in[18];

    int* out = (int*)d_out;
    const int max_len = out_size / BATCH;   // 64
    char* ws = (char*)d_ws;

    const size_t NEED = 103547136;

    if (ws_size >= NEED) {
        short* Wf1hi = (short*)(ws + 0);          //  9,437,184 B
        short* Wf1lo = (short*)(ws + 9437184);
        short* Wf2hi = (short*)(ws + 18874368);   // 37,748,736 B
        short* Wf2lo = (short*)(ws + 56623104);
        short* XB0hi = (short*)(ws + 94371840);   //     65,536 B
        short* XB0lo = (short*)(ws + 94437376);
        short* XB1hi[2] = { (short*)(ws + 94502912), (short*)(ws + 94765056) };
        short* XB1lo[2] = { (short*)(ws + 94633984), (short*)(ws + 94896128) };
        short* XB2hi[2] = { (short*)(ws + 95027200), (short*)(ws + 95551488) };
        short* XB2lo[2] = { (short*)(ws + 95289344), (short*)(ws + 95813632) };
        float* h0a = (float*)(ws + 96075776);
        float* h0b = (float*)(ws + 96206848);
        float* h1  = (float*)(ws + 96337920);
        float* h2  = (float*)(ws + 96600064);
        float* zT4 = (float*)(ws + 97124352);
        float* G1  = (float*)(ws + 97255424);     // 2,097,152 B (8 planes)
        float* G2  = (float*)(ws + 99352576);     // 4,194,304 B (8 planes)
        int*   dec = (int*)  (ws + 103546880);

        // ---- setup ----
        wtrans_l1<<<2304, 256, 0, stream>>>(w_ih1, w_hh1, Wf1hi, Wf1lo);
        wtrans_l2<<<9216, 256, 0, stream>>>(w_ih2, w_hh2, Wf2hi, Wf2lo);
        init_misc<<<32, 256, 0, stream>>>(z, zT4, dec, start_tok);
        init_hstate<<<896, 256, 0, stream>>>(zT4, fc_init_w, fc_init_b, h0a, h1, h2);
        initfrag<<<256, 256, 0, stream>>>(h1, XB1hi[0], XB1lo[0]);
        initfrag<<<512, 256, 0, stream>>>(h2, XB2hi[0], XB2lo[0]);

        for (int s = 0; s < max_len; ++s) {
            const int pi = s & 1, po = pi ^ 1;
            const float* h0i = pi ? h0b : h0a;
            float*       h0o = pi ? h0a : h0b;
            gru_l0<<<256, 512, 0, stream>>>(emb, dec, h0i, h0o,
                                            w_ih0, w_hh0, b_ih0, b_hh0,
                                            XB0hi, XB0lo);
            mfma_l1<<<384, 512, 0, stream>>>(Wf1hi, Wf1lo, XB0hi, XB0lo,
                                             XB1hi[pi], XB1lo[pi], G1);
            comb_l1<<<256, 256, 0, stream>>>(G1, b_ih1, b_hh1, h1,
                                             XB1hi[po], XB1lo[po]);
            // MT=2: 32 units/block -> 3 gates x 64 jb x 2 kq = 384 blocks
            mfma_l2<<<384, 512, 0, stream>>>(Wf2hi, Wf2lo, XB1hi[po], XB1lo[po],
                                             XB2hi[pi], XB2lo[pi], G2);
            comb_l2<<<512, 256, 0, stream>>>(G2, b_ih2, b_hh2, h2,
                                             XB2hi[po], XB2lo[po]);
            out_k<<<64, 512, 0, stream>>>(h2, fc_out_w, dec, out, s, max_len);
        }
    } else {
        // -------- fallback: round-3 path --------
        float* zT4    = (float*)(ws + 0);
        float* h0b2[2] = { (float*)(ws + 131072), (float*)(ws + 262144) };
        float* h1b2[2] = { (float*)(ws + 393216), (float*)(ws + 655360) };
        float* h2b2[2] = { (float*)(ws + 917504), (float*)(ws + 1441792) };
        int*   dec    = (int*)(ws + 1966080);

        init_misc<<<32, 256, 0, stream>>>(z, zT4, dec, start_tok);
        init_hstate<<<896, 256, 0, stream>>>(zT4, fc_init_w, fc_init_b,
                                             h0b2[0], h1b2[0], h2b2[0]);
        for (int s = 0; s < max_len; ++s) {
            const int pi = s & 1, po = pi ^ 1;
            gru_l0<<<256, 512, 0, stream>>>(emb, dec, h0b2[pi], h0b2[po],
                                            w_ih0, w_hh0, b_ih0, b_hh0,
                                            nullptr, nullptr);
            gru_fb1<<<256, 512, 0, stream>>>(h0b2[po], h1b2[pi], h1b2[po],
                                             w_ih1, w_hh1, b_ih1, b_hh1);
            gru_fb2<<<512, 512, 0, stream>>>(h1b2[po], h2b2[pi], h2b2[po],
                                             w_ih2, w_hh2, b_ih2, b_hh2);
            out_k<<<64, 512, 0, stream>>>(h2b2[po], fc_out_w, dec, out, s, max_len);
        }
    }
}